// Round 1
// baseline (382.311 us; speedup 1.0000x reference)
//
#include <hip/hip_runtime.h>
#include <hip/hip_bf16.h>

#define TT 512
#define BB 256
#define NN 128

// Forward algorithm: one workgroup per batch element b.
// alpha recurrence done as  p = exp(u - d);  S = p @ E;  u' = d + log(S) + emit_t
// with E = exp(trans) held in registers (64 floats per thread, 256 threads).
__global__ __launch_bounds__(256) void crf_forward(
    const float* __restrict__ emit, const void* __restrict__ maskp,
    const float* __restrict__ trans, const float* __restrict__ strans,
    const float* __restrict__ etrans, float* __restrict__ ws) {
  __shared__ __align__(16) float sh_p[NN];
  __shared__ float sh_part[256];
  __shared__ float sh_d;
  __shared__ int sh_ri[4];
  __shared__ float sh_rf[4];

  const int tid = threadIdx.x;
  const int b = blockIdx.x;
  const int j = tid & (NN - 1);
  const int h = tid >> 7;  // split-K half: waves 0,1 -> i in [0,64), waves 2,3 -> [64,128)

  // ---- mask dtype detection (+ length of this sequence) ----
  // mask[0,:] is all-true (lengths >= 1). If stored as u8, byte 1 == 1;
  // if stored as int32 (or float32 1.0f), byte 1 == 0.
  const unsigned char* mk8 = (const unsigned char*)maskp;
  const int* mk32 = (const int*)maskp;
  const bool is_u8 = (mk8[1] != 0);
  int cnt = 0;
  for (int t = tid; t < TT; t += 256) {
    int m = is_u8 ? (mk8[t * BB + b] != 0) : (mk32[t * BB + b] != 0);
    cnt += m;
  }
#pragma unroll
  for (int off = 32; off; off >>= 1) cnt += __shfl_down(cnt, off, 64);
  if ((tid & 63) == 0) sh_ri[tid >> 6] = cnt;
  __syncthreads();
  const int len = sh_ri[0] + sh_ri[1] + sh_ri[2] + sh_ri[3];

  // ---- E = exp(trans) into registers: e[k] = exp(trans[h*64+k][j]) ----
  float e[64];
#pragma unroll
  for (int k = 0; k < 64; ++k)
    e[k] = __expf(trans[(h * 64 + k) * NN + j]);

  // ---- init alpha (t = 0) ----
  float u = 0.f;
  if (tid < NN) u = strans[j] + emit[(size_t)b * NN + j];
  if (tid == 0) sh_d = u;

  // ---- preload emit for first group of 8 steps (t = 1..8) ----
  float ebuf[8];
  if (tid < NN) {
#pragma unroll
    for (int k = 0; k < 8; ++k) {
      int t = 1 + k;
      ebuf[k] = (t < TT) ? emit[((size_t)t * BB + b) * NN + j] : 0.f;
    }
  }
  __syncthreads();

  const int ngroups = (len + 6) / 8;  // steps t = 1..len-1, groups of 8
  for (int g = 0; g < ngroups; ++g) {
    const int tbase = 1 + g * 8;

    // prefetch next group's emit rows (hides HBM latency behind 8 steps)
    float enext[8];
    if (tid < NN) {
#pragma unroll
      for (int k = 0; k < 8; ++k) {
        int t = tbase + 8 + k;
        enext[k] = (t < TT) ? emit[((size_t)t * BB + b) * NN + j] : 0.f;
      }
    }

#pragma unroll
    for (int k = 0; k < 8; ++k) {
      const int t = tbase + k;
      const bool act = (t < len);
      const float d = sh_d;
      if (tid < NN) {
        sh_p[j] = __expf(u - d);
      }
      __syncthreads();

      // acc_j (this half-K) = sum_i p[i] * E[i][j]
      float acc = 0.f;
      const float4* p4 = reinterpret_cast<const float4*>(sh_p) + h * 16;
#pragma unroll
      for (int c = 0; c < 16; ++c) {
        float4 pv = p4[c];
        acc = fmaf(pv.x, e[4 * c + 0], acc);
        acc = fmaf(pv.y, e[4 * c + 1], acc);
        acc = fmaf(pv.z, e[4 * c + 2], acc);
        acc = fmaf(pv.w, e[4 * c + 3], acc);
      }
      sh_part[tid] = acc;
      __syncthreads();

      if (tid < NN && act) {
        float s = sh_part[j] + sh_part[j + NN];
        u = d + __logf(s) + ebuf[k];
        if (tid == 0) sh_d = u;
      }
      __syncthreads();
    }

    if (tid < NN) {
#pragma unroll
      for (int k = 0; k < 8; ++k) ebuf[k] = enext[k];
    }
  }

  // ---- final logsumexp over (u + etrans), add to ws[0] ----
  const float d = sh_d;
  float w = 0.f;
  if (tid < NN) w = __expf(u + etrans[j] - d);
#pragma unroll
  for (int off = 32; off; off >>= 1) w += __shfl_down(w, off, 64);
  if ((tid & 63) == 0) sh_rf[tid >> 6] = w;
  __syncthreads();
  if (tid == 0) {
    float s = sh_rf[0] + sh_rf[1] + sh_rf[2] + sh_rf[3];
    atomicAdd(&ws[0], d + __logf(s));
  }
}

// Gold-path score: one workgroup per batch element.
__global__ __launch_bounds__(256) void crf_score(
    const float* __restrict__ emit, const int* __restrict__ target,
    const void* __restrict__ maskp, const float* __restrict__ trans,
    const float* __restrict__ strans, const float* __restrict__ etrans,
    float* __restrict__ ws) {
  __shared__ float rf[4];
  __shared__ int ri[4];
  const int tid = threadIdx.x;
  const int b = blockIdx.x;
  const unsigned char* mk8 = (const unsigned char*)maskp;
  const int* mk32 = (const int*)maskp;
  const bool is_u8 = (mk8[1] != 0);

  float sc = 0.f;
  int cnt = 0;
  for (int t = tid; t < TT; t += 256) {
    int m = is_u8 ? (mk8[t * BB + b] != 0) : (mk32[t * BB + b] != 0);
    cnt += m;
    if (m) {
      int tg = target[t * BB + b];
      float v = emit[((size_t)t * BB + b) * NN + tg];
      if (t > 0) v += trans[target[(t - 1) * BB + b] * NN + tg];
      sc += v;
    }
  }
#pragma unroll
  for (int off = 32; off; off >>= 1) {
    sc += __shfl_down(sc, off, 64);
    cnt += __shfl_down(cnt, off, 64);
  }
  if ((tid & 63) == 0) {
    rf[tid >> 6] = sc;
    ri[tid >> 6] = cnt;
  }
  __syncthreads();
  if (tid == 0) {
    float tot = rf[0] + rf[1] + rf[2] + rf[3];
    int len = ri[0] + ri[1] + ri[2] + ri[3];
    tot += strans[target[b]];                            // start transition
    tot += etrans[target[(size_t)(len - 1) * BB + b]];   // end transition
    atomicAdd(&ws[1], tot);
  }
}

__global__ void crf_fin(const float* __restrict__ ws, float* __restrict__ out) {
  out[0] = (ws[0] - ws[1]) * (1.0f / (float)BB);
}

extern "C" void kernel_launch(void* const* d_in, const int* in_sizes, int n_in,
                              void* d_out, int out_size, void* d_ws, size_t ws_size,
                              hipStream_t stream) {
  const float* emit = (const float*)d_in[0];
  const int* target = (const int*)d_in[1];
  const void* mask = (const void*)d_in[2];
  const float* trans = (const float*)d_in[3];
  const float* strans = (const float*)d_in[4];
  const float* etrans = (const float*)d_in[5];
  float* ws = (float*)d_ws;
  float* out = (float*)d_out;

  hipMemsetAsync(d_ws, 0, 2 * sizeof(float), stream);
  crf_forward<<<BB, 256, 0, stream>>>(emit, mask, trans, strans, etrans, ws);
  crf_score<<<BB, 256, 0, stream>>>(emit, target, mask, trans, strans, etrans, ws);
  crf_fin<<<1, 1, 0, stream>>>(ws, out);
}

// Round 2
// 368.776 us; speedup vs baseline: 1.0367x; 1.0367x over previous
//
#include <hip/hip_runtime.h>
#include <hip/hip_bf16.h>

#define TT 512
#define BB 256
#define NN 128

// Forward algorithm: one workgroup per batch element b.
//   p = exp(u - d);  S = p @ E;  u' = d + log(S) + emit_t
// E = exp(trans) held in registers: 64 floats/thread (split-K halves).
// d (normalizer) is read from LDS one barrier-interval late -> stale by 2
// steps, which is numerically safe (same d subtracted and re-added) and
// removes the third barrier per step.
__global__ __launch_bounds__(256, 1) void crf_forward(
    const float* __restrict__ emit, const void* __restrict__ maskp,
    const float* __restrict__ trans, const float* __restrict__ strans,
    const float* __restrict__ etrans, float* __restrict__ ws) {
  __shared__ __align__(16) float sh_p[NN];
  __shared__ float sh_part[256];
  __shared__ float sh_d;
  __shared__ int sh_ri[4];
  __shared__ float sh_rf[4];

  const int tid = threadIdx.x;
  const int b = blockIdx.x;
  const int j = tid & (NN - 1);
  const int h = tid >> 7;  // split-K half: waves 0,1 -> i in [0,64), waves 2,3 -> [64,128)

  // ---- mask dtype detection (+ length of this sequence) ----
  const unsigned char* mk8 = (const unsigned char*)maskp;
  const int* mk32 = (const int*)maskp;
  const bool is_u8 = (mk8[1] != 0);
  int cnt = 0;
  for (int t = tid; t < TT; t += 256) {
    int m = is_u8 ? (mk8[t * BB + b] != 0) : (mk32[t * BB + b] != 0);
    cnt += m;
  }
#pragma unroll
  for (int off = 32; off; off >>= 1) cnt += __shfl_down(cnt, off, 64);
  if ((tid & 63) == 0) sh_ri[tid >> 6] = cnt;
  __syncthreads();
  const int len = sh_ri[0] + sh_ri[1] + sh_ri[2] + sh_ri[3];

  // ---- E = exp(trans) into registers: e[k] = exp(trans[h*64+k][j]) ----
  float e[64];
#pragma unroll
  for (int k = 0; k < 64; ++k)
    e[k] = __expf(trans[(h * 64 + k) * NN + j]);

  // ---- init alpha (t = 0) ----
  float u = 0.f;
  float d_reg = 0.f;
  if (tid < NN) u = strans[j] + emit[(size_t)b * NN + j];
  if (tid == 0) sh_d = u;

  // ---- preload emit for first group of 8 steps (t = 1..8) ----
  float ebuf[8];
  if (tid < NN) {
#pragma unroll
    for (int k = 0; k < 8; ++k) {
      int t = 1 + k;
      ebuf[k] = (t < TT) ? emit[((size_t)t * BB + b) * NN + j] : 0.f;
    }
  }
  __syncthreads();
  if (tid < NN) d_reg = sh_d;  // u_0 at t=0

  const int ngroups = (len + 6) / 8;  // steps t = 1..len-1, groups of 8
  for (int g = 0; g < ngroups; ++g) {
    const int tbase = 1 + g * 8;

    // prefetch next group's emit rows (hides HBM latency behind 8 steps)
    float enext[8];
    if (tid < NN) {
#pragma unroll
      for (int k = 0; k < 8; ++k) {
        int t = tbase + 8 + k;
        enext[k] = (t < TT) ? emit[((size_t)t * BB + b) * NN + j] : 0.f;
      }
    }

#pragma unroll
    for (int k = 0; k < 8; ++k) {
      const int t = tbase + k;
      const bool act = (t < len);
      // write p with the (stale-by-2) normalizer
      if (tid < NN) sh_p[j] = __expf(u - d_reg);
      __syncthreads();  // barrier A

      // acc_j (this half-K) = sum_i p[i] * E[i][j]
      float acc = 0.f;
      const float4* p4 = reinterpret_cast<const float4*>(sh_p) + h * 16;
#pragma unroll
      for (int c = 0; c < 16; ++c) {
        float4 pv = p4[c];
        acc = fmaf(pv.x, e[4 * c + 0], acc);
        acc = fmaf(pv.y, e[4 * c + 1], acc);
        acc = fmaf(pv.z, e[4 * c + 2], acc);
        acc = fmaf(pv.w, e[4 * c + 3], acc);
      }
      sh_part[tid] = acc;
      float d_next = d_reg;
      if (tid < NN) d_next = sh_d;  // read after barrier A: written 2 steps ago
      __syncthreads();  // barrier B

      if (tid < NN && act) {
        float s = sh_part[j] + sh_part[j + NN];
        u = d_reg + __logf(s) + ebuf[k];
        if (tid == 0) sh_d = u;  // written after B, read after next A
      }
      if (tid < NN) d_reg = d_next;
    }

    if (tid < NN) {
#pragma unroll
      for (int k = 0; k < 8; ++k) ebuf[k] = enext[k];
    }
  }

  // ---- final logsumexp over (u + etrans), add to ws[0] ----
  float w = 0.f;
  if (tid < NN) w = __expf(u + etrans[j] - d_reg);
#pragma unroll
  for (int off = 32; off; off >>= 1) w += __shfl_down(w, off, 64);
  if ((tid & 63) == 0) sh_rf[tid >> 6] = w;
  __syncthreads();
  if (tid == 0) {
    float s = sh_rf[0] + sh_rf[1] + sh_rf[2] + sh_rf[3];
    atomicAdd(&ws[0], d_reg + __logf(s));
  }
}

// Gold-path score: one workgroup per batch element.
__global__ __launch_bounds__(256) void crf_score(
    const float* __restrict__ emit, const int* __restrict__ target,
    const void* __restrict__ maskp, const float* __restrict__ trans,
    const float* __restrict__ strans, const float* __restrict__ etrans,
    float* __restrict__ ws) {
  __shared__ float rf[4];
  __shared__ int ri[4];
  const int tid = threadIdx.x;
  const int b = blockIdx.x;
  const unsigned char* mk8 = (const unsigned char*)maskp;
  const int* mk32 = (const int*)maskp;
  const bool is_u8 = (mk8[1] != 0);

  float sc = 0.f;
  int cnt = 0;
  for (int t = tid; t < TT; t += 256) {
    int m = is_u8 ? (mk8[t * BB + b] != 0) : (mk32[t * BB + b] != 0);
    cnt += m;
    if (m) {
      int tg = target[t * BB + b];
      float v = emit[((size_t)t * BB + b) * NN + tg];
      if (t > 0) v += trans[target[(t - 1) * BB + b] * NN + tg];
      sc += v;
    }
  }
#pragma unroll
  for (int off = 32; off; off >>= 1) {
    sc += __shfl_down(sc, off, 64);
    cnt += __shfl_down(cnt, off, 64);
  }
  if ((tid & 63) == 0) {
    rf[tid >> 6] = sc;
    ri[tid >> 6] = cnt;
  }
  __syncthreads();
  if (tid == 0) {
    float tot = rf[0] + rf[1] + rf[2] + rf[3];
    int len = ri[0] + ri[1] + ri[2] + ri[3];
    tot += strans[target[b]];                            // start transition
    tot += etrans[target[(size_t)(len - 1) * BB + b]];   // end transition
    atomicAdd(&ws[1], tot);
  }
}

__global__ void crf_fin(const float* __restrict__ ws, float* __restrict__ out) {
  out[0] = (ws[0] - ws[1]) * (1.0f / (float)BB);
}

extern "C" void kernel_launch(void* const* d_in, const int* in_sizes, int n_in,
                              void* d_out, int out_size, void* d_ws, size_t ws_size,
                              hipStream_t stream) {
  const float* emit = (const float*)d_in[0];
  const int* target = (const int*)d_in[1];
  const void* mask = (const void*)d_in[2];
  const float* trans = (const float*)d_in[3];
  const float* strans = (const float*)d_in[4];
  const float* etrans = (const float*)d_in[5];
  float* ws = (float*)d_ws;
  float* out = (float*)d_out;

  hipMemsetAsync(d_ws, 0, 2 * sizeof(float), stream);
  crf_forward<<<BB, 256, 0, stream>>>(emit, mask, trans, strans, etrans, ws);
  crf_score<<<BB, 256, 0, stream>>>(emit, target, mask, trans, strans, etrans, ws);
  crf_fin<<<1, 1, 0, stream>>>(ws, out);
}